// Round 4
// baseline (3380.665 us; speedup 1.0000x reference)
//
#include <hip/hip_runtime.h>
#include <math.h>

static constexpr int IN_DIM  = 128;
static constexpr int HID     = 64;
static constexpr int OUT_F   = 32;
static constexpr int NUM_LBL = 10;

// bf16 pack/unpack via bit ops (ROCm bf16 API surface is unreliable across versions)
__device__ __forceinline__ unsigned int f2bf_lo(float f) {   // bf16 bits in low 16
    unsigned int u = __float_as_uint(f);
    return (u + 0x7fffu + ((u >> 16) & 1u)) >> 16;
}
__device__ __forceinline__ unsigned int pack_bf2(float a, float b) {
    return f2bf_lo(a) | (f2bf_lo(b) << 16);
}
__device__ __forceinline__ float bf2f_lo(unsigned int v) { return __uint_as_float(v << 16); }
__device__ __forceinline__ float bf2f_hi(unsigned int v) { return __uint_as_float(v & 0xffff0000u); }

// ---------------- graph setup kernels ----------------

__global__ void count_deg_k(const int* __restrict__ dst, int* __restrict__ deg, int E) {
    int e = blockIdx.x * 256 + threadIdx.x;
    if (e < E) atomicAdd(&deg[dst[e]], 1);
}

__global__ void dinv_k(const int* __restrict__ deg, float* __restrict__ dinv, int n) {
    int i = blockIdx.x * 256 + threadIdx.x;
    if (i < n) dinv[i] = rsqrtf((float)deg[i] + 1.0f);
}

__global__ void scan_partials_k(const int* __restrict__ deg, int* __restrict__ partials, int n) {
    __shared__ int s[256];
    int i = blockIdx.x * 256 + threadIdx.x;
    s[threadIdx.x] = (i < n) ? deg[i] : 0;
    __syncthreads();
    for (int st = 128; st > 0; st >>= 1) {
        if (threadIdx.x < st) s[threadIdx.x] += s[threadIdx.x + st];
        __syncthreads();
    }
    if (threadIdx.x == 0) partials[blockIdx.x] = s[0];
}

// single block, exclusive scan in place (nb <= 512)
__global__ void scan_top_k(int* __restrict__ partials, int nb) {
    __shared__ int s[512];
    int t = threadIdx.x;
    int v = (t < nb) ? partials[t] : 0;
    s[t] = v;
    __syncthreads();
    for (int off = 1; off < 512; off <<= 1) {
        int x = (t >= off) ? s[t - off] : 0;
        __syncthreads();
        s[t] += x;
        __syncthreads();
    }
    if (t < nb) partials[t] = s[t] - v;
}

__global__ void scan_final_k(const int* __restrict__ deg, const int* __restrict__ partials,
                             int* __restrict__ row_ptr, int* __restrict__ cursor, int n, int E) {
    __shared__ int s[256];
    int t = threadIdx.x;
    int i = blockIdx.x * 256 + t;
    int v = (i < n) ? deg[i] : 0;
    s[t] = v;
    __syncthreads();
    for (int off = 1; off < 256; off <<= 1) {
        int x = (t >= off) ? s[t - off] : 0;
        __syncthreads();
        s[t] += x;
        __syncthreads();
    }
    int excl = s[t] - v + partials[blockIdx.x];
    if (i < n) { row_ptr[i] = excl; cursor[i] = excl; }
    if (i == 0) row_ptr[n] = E;
}

__global__ void fill_csr_k(const int* __restrict__ src, const int* __restrict__ dst,
                           int* __restrict__ cursor, int* __restrict__ col, int E) {
    int e = blockIdx.x * 256 + threadIdx.x;
    if (e < E) {
        int pos = atomicAdd(&cursor[dst[e]], 1);
        col[pos] = src[e];
    }
}

// ---------------- compute kernels ----------------

// g[row, 2c2..2c2+1] = bf16x2( dinv[row] * x[row,:] @ W[:, 2c2..2c2+1] )
// Block stages W once, then processes CHUNK=64 rows (amortizes staging 8-16x).
template<int K, int F>
__global__ void linear_scale_k(const float* __restrict__ x, const float* __restrict__ W,
                               const float* __restrict__ dinv,
                               unsigned int* __restrict__ g, int n) {
    constexpr int L = F / 2;            // packed cols per row
    constexpr int RPP = 256 / L;        // rows per pass
    constexpr int CHUNK = 64;
    __shared__ float Ws[K * F];
    {   // vectorized staging
        const float4* W4 = (const float4*)W;
        float4* Ws4 = (float4*)Ws;
        for (int idx = threadIdx.x; idx < K * F / 4; idx += 256) Ws4[idx] = W4[idx];
    }
    __syncthreads();
    const float2* Ws2 = (const float2*)Ws;
    int c2 = threadIdx.x % L;
    int rend = min(n, (int)(blockIdx.x * CHUNK + CHUNK));
    for (int r = blockIdx.x * CHUNK + threadIdx.x / L; r < rend; r += RPP) {
        const float4* x4 = (const float4*)(x + (size_t)r * K);
        float2 acc = {0.f, 0.f};
#pragma unroll
        for (int k4 = 0; k4 < K / 4; ++k4) {
            float4 xv = x4[k4];
            float2 w0 = Ws2[(4 * k4 + 0) * L + c2];
            float2 w1 = Ws2[(4 * k4 + 1) * L + c2];
            float2 w2 = Ws2[(4 * k4 + 2) * L + c2];
            float2 w3 = Ws2[(4 * k4 + 3) * L + c2];
            acc.x += xv.x * w0.x; acc.y += xv.x * w0.y;
            acc.x += xv.y * w1.x; acc.y += xv.y * w1.y;
            acc.x += xv.z * w2.x; acc.y += xv.z * w2.y;
            acc.x += xv.w * w3.x; acc.y += xv.w * w3.y;
        }
        float di = dinv[r];
        g[(size_t)r * L + c2] = pack_bf2(di * acc.x, di * acc.y);
    }
}

// out[i,:] = dinv[i] * (sum_{src in nbr(i)} g[src,:] + g[i,:]) + bias; optional mask overwrite.
// One node per WAVE; lanes = L packed-slots x S edge-splits; shfl_xor reduce over splits.
template<int F, bool MASK>
__global__ void gcn_gather_k(const unsigned int* __restrict__ g, const int* __restrict__ row_ptr,
                             const int* __restrict__ col, const float* __restrict__ dinv,
                             const float* __restrict__ bias, const int* __restrict__ mask,
                             const float* __restrict__ y, float* __restrict__ out, int n) {
    constexpr int L = F / 2;            // packed lanes per node
    constexpr int S = 64 / L;           // edge-split ways (F=64 -> 2, F=32 -> 4)
    int lane = threadIdx.x & 63;
    int wid  = threadIdx.x >> 6;
    int c2 = lane % L;
    int sp = lane / L;
    int i = blockIdx.x * 4 + wid;
    if (i >= n) return;
    int beg = row_ptr[i], end = row_ptr[i + 1];
    float2 acc = {0.f, 0.f};
    for (int p = beg + sp; p < end; p += S) {
        int s = col[p];
        unsigned int v = g[(size_t)s * L + c2];
        acc.x += bf2f_lo(v);
        acc.y += bf2f_hi(v);
    }
#pragma unroll
    for (int m = 32; m >= L; m >>= 1) {
        acc.x += __shfl_xor(acc.x, m);
        acc.y += __shfl_xor(acc.y, m);
    }
    if (sp == 0) {
        unsigned int gi = g[(size_t)i * L + c2];
        float di = dinv[i];
        float2 v;
        v.x = di * (acc.x + bf2f_lo(gi)) + bias[2 * c2];
        v.y = di * (acc.y + bf2f_hi(gi)) + bias[2 * c2 + 1];
        if (MASK) {
            if (mask[i]) v = ((const float2*)y)[(size_t)i * L + c2];
        }
        ((float2*)out)[(size_t)i * L + c2] = v;
    }
}

// out[i,:] = sigmoid( [h|xl|dw] @ Wf + bf ), chunked rows, staged W, float2 cols
__global__ void fuse_k(const float* __restrict__ h, const float* __restrict__ xl,
                       const float* __restrict__ dw, const float* __restrict__ Wf,
                       const float* __restrict__ bf, float* __restrict__ out, int n) {
    constexpr int L = 16;               // 16 f2-slots = 32 cols
    constexpr int RPP = 16;
    constexpr int CHUNK = 64;
    __shared__ float Ws[160 * 32];
    {
        const float4* W4 = (const float4*)Wf;
        float4* Ws4 = (float4*)Ws;
        for (int idx = threadIdx.x; idx < 160 * 32 / 4; idx += 256) Ws4[idx] = W4[idx];
    }
    __syncthreads();
    const float2* Ws2 = (const float2*)Ws;
    int c2 = threadIdx.x % L;
    int rend = min(n, (int)(blockIdx.x * CHUNK + CHUNK));
    for (int r = blockIdx.x * CHUNK + threadIdx.x / L; r < rend; r += RPP) {
        float2 acc = {bf[2 * c2], bf[2 * c2 + 1]};
        const float4* h4 = (const float4*)(h + (size_t)r * 64);
#pragma unroll
        for (int k4 = 0; k4 < 16; ++k4) {
            float4 v = h4[k4]; int kb = k4 * 4;
            float2 w0 = Ws2[(kb + 0) * L + c2], w1 = Ws2[(kb + 1) * L + c2];
            float2 w2 = Ws2[(kb + 2) * L + c2], w3 = Ws2[(kb + 3) * L + c2];
            acc.x += v.x * w0.x; acc.y += v.x * w0.y;
            acc.x += v.y * w1.x; acc.y += v.y * w1.y;
            acc.x += v.z * w2.x; acc.y += v.z * w2.y;
            acc.x += v.w * w3.x; acc.y += v.w * w3.y;
        }
        const float4* x4 = (const float4*)(xl + (size_t)r * 32);
#pragma unroll
        for (int k4 = 0; k4 < 8; ++k4) {
            float4 v = x4[k4]; int kb = 64 + k4 * 4;
            float2 w0 = Ws2[(kb + 0) * L + c2], w1 = Ws2[(kb + 1) * L + c2];
            float2 w2 = Ws2[(kb + 2) * L + c2], w3 = Ws2[(kb + 3) * L + c2];
            acc.x += v.x * w0.x; acc.y += v.x * w0.y;
            acc.x += v.y * w1.x; acc.y += v.y * w1.y;
            acc.x += v.z * w2.x; acc.y += v.z * w2.y;
            acc.x += v.w * w3.x; acc.y += v.w * w3.y;
        }
        const float4* d4 = (const float4*)(dw + (size_t)r * 64);
#pragma unroll
        for (int k4 = 0; k4 < 16; ++k4) {
            float4 v = d4[k4]; int kb = 96 + k4 * 4;
            float2 w0 = Ws2[(kb + 0) * L + c2], w1 = Ws2[(kb + 1) * L + c2];
            float2 w2 = Ws2[(kb + 2) * L + c2], w3 = Ws2[(kb + 3) * L + c2];
            acc.x += v.x * w0.x; acc.y += v.x * w0.y;
            acc.x += v.y * w1.x; acc.y += v.y * w1.y;
            acc.x += v.z * w2.x; acc.y += v.z * w2.y;
            acc.x += v.w * w3.x; acc.y += v.w * w3.y;
        }
        float2 o;
        o.x = 1.0f / (1.0f + __expf(-acc.x));
        o.y = 1.0f / (1.0f + __expf(-acc.y));
        ((float2*)out)[(size_t)r * L + c2] = o;
    }
}

// ---------------- launch ----------------

extern "C" void kernel_launch(void* const* d_in, const int* in_sizes, int n_in,
                              void* d_out, int out_size, void* d_ws, size_t ws_size,
                              hipStream_t stream) {
    const float* x    = (const float*)d_in[0];
    const float* y    = (const float*)d_in[1];
    const int*   ei   = (const int*)  d_in[2];
    const float* dw   = (const float*)d_in[3];
    const int*   mask = (const int*)  d_in[4];
    const float* Wg0  = (const float*)d_in[5];
    const float* bg0  = (const float*)d_in[6];
    const float* Wg1  = (const float*)d_in[7];
    const float* bg1  = (const float*)d_in[8];
    const float* Wl   = (const float*)d_in[9];
    const float* bl   = (const float*)d_in[10];
    const float* Wf   = (const float*)d_in[11];
    const float* bf   = (const float*)d_in[12];
    float* out = (float*)d_out;

    const int N = in_sizes[0] / IN_DIM;
    const int E = in_sizes[2] / 2;
    const int* src = ei;
    const int* dst = ei + E;

    char* w = (char*)d_ws;
    size_t off = 0;
    auto alloc = [&](size_t bytes) -> char* {
        off = (off + 255) & ~(size_t)255;
        char* p = w + off; off += bytes; return p;
    };
    float* dinv   = (float*)alloc((size_t)N * 4);
    int*   deg    = (int*)  alloc((size_t)N * 4);
    int*   rowp   = (int*)  alloc((size_t)(N + 1) * 4);
    int*   cursor = (int*)  alloc((size_t)N * 4);
    int*   parts  = (int*)  alloc(512 * 4);
    int*   colx   = (int*)  alloc((size_t)E * 4);
    unsigned int* gbuf = (unsigned int*)alloc((size_t)N * (HID / 2) * 4);
    float* hbuf   = (float*)alloc((size_t)N * HID * 4);
    float* xlA    = (float*)alloc((size_t)N * OUT_F * 4);
    float* xlB    = (float*)alloc((size_t)N * OUT_F * 4);
    (void)ws_size; (void)n_in; (void)out_size;

    const int nbN = (N + 255) / 256;
    const int nbE = (E + 255) / 256;
    const int nbC = (N + 63) / 64;      // 64-row chunks
    const int nbG = (N + 3) / 4;        // one node per wave, 4 waves/block

    (void)hipMemsetAsync(deg, 0, (size_t)N * 4, stream);
    count_deg_k<<<nbE, 256, 0, stream>>>(dst, deg, E);
    dinv_k<<<nbN, 256, 0, stream>>>(deg, dinv, N);
    scan_partials_k<<<nbN, 256, 0, stream>>>(deg, parts, N);
    scan_top_k<<<1, 512, 0, stream>>>(parts, nbN);
    scan_final_k<<<nbN, 256, 0, stream>>>(deg, parts, rowp, cursor, N, E);
    fill_csr_k<<<nbE, 256, 0, stream>>>(src, dst, cursor, colx, E);

    // feature path
    linear_scale_k<IN_DIM, HID><<<nbC, 256, 0, stream>>>(x, Wg0, dinv, gbuf, N);
    gcn_gather_k<HID, false><<<nbG, 256, 0, stream>>>(gbuf, rowp, colx, dinv, bg0, nullptr, nullptr, hbuf, N);
    linear_scale_k<HID, HID><<<nbC, 256, 0, stream>>>(hbuf, Wg1, dinv, gbuf, N);
    gcn_gather_k<HID, false><<<nbG, 256, 0, stream>>>(gbuf, rowp, colx, dinv, bg1, nullptr, nullptr, hbuf, N);

    // label path: 10 masked convs, ping-pong xlA/xlB
    const float* xl_cur = y;
    for (int j = 0; j < NUM_LBL; ++j) {
        float* xl_out = (j & 1) ? xlB : xlA;
        linear_scale_k<OUT_F, OUT_F><<<nbC, 256, 0, stream>>>(xl_cur, Wl + (size_t)j * OUT_F * OUT_F, dinv, gbuf, N);
        gcn_gather_k<OUT_F, true><<<nbG, 256, 0, stream>>>(gbuf, rowp, colx, dinv, bl + (size_t)j * OUT_F, mask, y, xl_out, N);
        xl_cur = xl_out;
    }

    fuse_k<<<nbC, 256, 0, stream>>>(hbuf, xl_cur, dw, Wf, bf, out, N);
}

// Round 5
// 1940.000 us; speedup vs baseline: 1.7426x; 1.7426x over previous
//
#include <hip/hip_runtime.h>
#include <math.h>

static constexpr int IN_DIM  = 128;
static constexpr int HID     = 64;
static constexpr int OUT_F   = 32;
static constexpr int NUM_LBL = 10;

// bf16 pack/unpack via bit ops (ROCm bf16 API surface is unreliable across versions)
__device__ __forceinline__ unsigned int f2bf_lo(float f) {   // bf16 bits in low 16
    unsigned int u = __float_as_uint(f);
    return (u + 0x7fffu + ((u >> 16) & 1u)) >> 16;
}
__device__ __forceinline__ unsigned int pack_bf2(float a, float b) {
    return f2bf_lo(a) | (f2bf_lo(b) << 16);
}
__device__ __forceinline__ float bf2f_lo(unsigned int v) { return __uint_as_float(v << 16); }
__device__ __forceinline__ float bf2f_hi(unsigned int v) { return __uint_as_float(v & 0xffff0000u); }

// ---------------- graph setup kernels ----------------

__global__ void count_deg_k(const int* __restrict__ dst, int* __restrict__ deg, int E) {
    int e = blockIdx.x * 256 + threadIdx.x;
    if (e < E) atomicAdd(&deg[dst[e]], 1);
}

__global__ void dinv_k(const int* __restrict__ deg, float* __restrict__ dinv, int n) {
    int i = blockIdx.x * 256 + threadIdx.x;
    if (i < n) dinv[i] = rsqrtf((float)deg[i] + 1.0f);
}

__global__ void scan_partials_k(const int* __restrict__ deg, int* __restrict__ partials, int n) {
    __shared__ int s[256];
    int i = blockIdx.x * 256 + threadIdx.x;
    s[threadIdx.x] = (i < n) ? deg[i] : 0;
    __syncthreads();
    for (int st = 128; st > 0; st >>= 1) {
        if (threadIdx.x < st) s[threadIdx.x] += s[threadIdx.x + st];
        __syncthreads();
    }
    if (threadIdx.x == 0) partials[blockIdx.x] = s[0];
}

// single block, exclusive scan in place (nb <= 512)
__global__ void scan_top_k(int* __restrict__ partials, int nb) {
    __shared__ int s[512];
    int t = threadIdx.x;
    int v = (t < nb) ? partials[t] : 0;
    s[t] = v;
    __syncthreads();
    for (int off = 1; off < 512; off <<= 1) {
        int x = (t >= off) ? s[t - off] : 0;
        __syncthreads();
        s[t] += x;
        __syncthreads();
    }
    if (t < nb) partials[t] = s[t] - v;
}

__global__ void scan_final_k(const int* __restrict__ deg, const int* __restrict__ partials,
                             int* __restrict__ row_ptr, int* __restrict__ cursor, int n, int E) {
    __shared__ int s[256];
    int t = threadIdx.x;
    int i = blockIdx.x * 256 + t;
    int v = (i < n) ? deg[i] : 0;
    s[t] = v;
    __syncthreads();
    for (int off = 1; off < 256; off <<= 1) {
        int x = (t >= off) ? s[t - off] : 0;
        __syncthreads();
        s[t] += x;
        __syncthreads();
    }
    int excl = s[t] - v + partials[blockIdx.x];
    if (i < n) { row_ptr[i] = excl; cursor[i] = excl; }
    if (i == 0) row_ptr[n] = E;
}

__global__ void fill_csr_k(const int* __restrict__ src, const int* __restrict__ dst,
                           int* __restrict__ cursor, int* __restrict__ col, int E) {
    int e = blockIdx.x * 256 + threadIdx.x;
    if (e < E) {
        int pos = atomicAdd(&cursor[dst[e]], 1);
        col[pos] = src[e];
    }
}

// ---------------- compute kernels ----------------

// g[row, 2c2..2c2+1] = bf16x2( dinv[row] * x[row,:] @ W[:, 2c2..2c2+1] )
// W AND the x-chunk staged in LDS: global reads are coalesced-once; row reuse
// is served by LDS broadcast (free). Row pad +4 floats keeps multi-row
// ds_read_b128 at <=4 distinct banks-groups (conflict-free for our strides).
template<int K, int F, int CHUNK>
__global__ void linear_scale_k(const float* __restrict__ x, const float* __restrict__ W,
                               const float* __restrict__ dinv,
                               unsigned int* __restrict__ g, int n) {
    constexpr int L = F / 2;            // packed col-pairs per row
    constexpr int RPP = 256 / L;        // rows per pass
    constexpr int KP = K + 4;           // padded row stride (floats)
    __shared__ float Ws[K * F];
    __shared__ float Xs[CHUNK * KP];
    __shared__ float Ds[CHUNK];
    {   // stage W (coalesced)
        const float4* W4 = (const float4*)W;
        float4* Ws4 = (float4*)Ws;
        for (int idx = threadIdx.x; idx < K * F / 4; idx += 256) Ws4[idx] = W4[idx];
    }
    int base = blockIdx.x * CHUNK;
    int nrows = min(CHUNK, n - base);
    {   // stage x chunk (coalesced global, padded LDS rows)
        const float4* X4 = (const float4*)(x + (size_t)base * K);
        for (int idx = threadIdx.x; idx < nrows * (K / 4); idx += 256) {
            int row = idx / (K / 4), kk = idx % (K / 4);
            *(float4*)(Xs + row * KP + kk * 4) = X4[idx];
        }
        if (threadIdx.x < nrows) Ds[threadIdx.x] = dinv[base + threadIdx.x];
    }
    __syncthreads();
    const float2* Ws2 = (const float2*)Ws;
    int c2 = threadIdx.x % L;
    for (int rl = threadIdx.x / L; rl < nrows; rl += RPP) {
        const float4* xr = (const float4*)(Xs + rl * KP);
        float2 acc = {0.f, 0.f};
#pragma unroll
        for (int k4 = 0; k4 < K / 4; ++k4) {
            float4 xv = xr[k4];
            float2 w0 = Ws2[(4 * k4 + 0) * L + c2];
            float2 w1 = Ws2[(4 * k4 + 1) * L + c2];
            float2 w2 = Ws2[(4 * k4 + 2) * L + c2];
            float2 w3 = Ws2[(4 * k4 + 3) * L + c2];
            acc.x += xv.x * w0.x; acc.y += xv.x * w0.y;
            acc.x += xv.y * w1.x; acc.y += xv.y * w1.y;
            acc.x += xv.z * w2.x; acc.y += xv.z * w2.y;
            acc.x += xv.w * w3.x; acc.y += xv.w * w3.y;
        }
        float di = Ds[rl];
        g[(size_t)(base + rl) * L + c2] = pack_bf2(di * acc.x, di * acc.y);
    }
}

// out[i,:] = dinv[i] * (sum_{src in nbr(i)} g[src,:] + g[i,:]) + bias; optional mask overwrite.
// One node per WAVE; lanes = L packed-slots x S edge-splits; shfl_xor reduce over splits.
template<int F, bool MASK>
__global__ void gcn_gather_k(const unsigned int* __restrict__ g, const int* __restrict__ row_ptr,
                             const int* __restrict__ col, const float* __restrict__ dinv,
                             const float* __restrict__ bias, const int* __restrict__ mask,
                             const float* __restrict__ y, float* __restrict__ out, int n) {
    constexpr int L = F / 2;            // packed lanes per node
    constexpr int S = 64 / L;           // edge-split ways (F=64 -> 2, F=32 -> 4)
    int lane = threadIdx.x & 63;
    int wid  = threadIdx.x >> 6;
    int c2 = lane % L;
    int sp = lane / L;
    int i = blockIdx.x * 4 + wid;
    if (i >= n) return;
    int beg = row_ptr[i], end = row_ptr[i + 1];
    float2 acc = {0.f, 0.f};
    for (int p = beg + sp; p < end; p += S) {
        int s = col[p];
        unsigned int v = g[(size_t)s * L + c2];
        acc.x += bf2f_lo(v);
        acc.y += bf2f_hi(v);
    }
#pragma unroll
    for (int m = 32; m >= L; m >>= 1) {
        acc.x += __shfl_xor(acc.x, m);
        acc.y += __shfl_xor(acc.y, m);
    }
    if (sp == 0) {
        unsigned int gi = g[(size_t)i * L + c2];
        float di = dinv[i];
        float2 v;
        v.x = di * (acc.x + bf2f_lo(gi)) + bias[2 * c2];
        v.y = di * (acc.y + bf2f_hi(gi)) + bias[2 * c2 + 1];
        if (MASK) {
            if (mask[i]) v = ((const float2*)y)[(size_t)i * L + c2];
        }
        ((float2*)out)[(size_t)i * L + c2] = v;
    }
}

// out[i,:] = sigmoid( [h|xl|dw] @ Wf + bf ); W + all three input chunks in LDS
__global__ void fuse_k(const float* __restrict__ h, const float* __restrict__ xl,
                       const float* __restrict__ dw, const float* __restrict__ Wf,
                       const float* __restrict__ bf, float* __restrict__ out, int n) {
    constexpr int L = 16;               // 16 f2-slots = 32 cols
    constexpr int RPP = 16;
    constexpr int CHUNK = 32;
    __shared__ float Ws[160 * 32];
    __shared__ float Hs[CHUNK * 68];    // 64 + 4 pad
    __shared__ float Xls[CHUNK * 36];   // 32 + 4 pad
    __shared__ float Dws[CHUNK * 68];
    {
        const float4* W4 = (const float4*)Wf;
        float4* Ws4 = (float4*)Ws;
        for (int idx = threadIdx.x; idx < 160 * 32 / 4; idx += 256) Ws4[idx] = W4[idx];
    }
    int base = blockIdx.x * CHUNK;
    int nrows = min(CHUNK, n - base);
    {
        const float4* H4 = (const float4*)(h + (size_t)base * 64);
        for (int idx = threadIdx.x; idx < nrows * 16; idx += 256) {
            int row = idx / 16, kk = idx % 16;
            *(float4*)(Hs + row * 68 + kk * 4) = H4[idx];
        }
        const float4* X4 = (const float4*)(xl + (size_t)base * 32);
        for (int idx = threadIdx.x; idx < nrows * 8; idx += 256) {
            int row = idx / 8, kk = idx % 8;
            *(float4*)(Xls + row * 36 + kk * 4) = X4[idx];
        }
        const float4* D4 = (const float4*)(dw + (size_t)base * 64);
        for (int idx = threadIdx.x; idx < nrows * 16; idx += 256) {
            int row = idx / 16, kk = idx % 16;
            *(float4*)(Dws + row * 68 + kk * 4) = D4[idx];
        }
    }
    __syncthreads();
    const float2* Ws2 = (const float2*)Ws;
    int c2 = threadIdx.x % L;
    for (int rl = threadIdx.x / L; rl < nrows; rl += RPP) {
        float2 acc = {bf[2 * c2], bf[2 * c2 + 1]};
        const float4* h4 = (const float4*)(Hs + rl * 68);
#pragma unroll
        for (int k4 = 0; k4 < 16; ++k4) {
            float4 v = h4[k4]; int kb = k4 * 4;
            float2 w0 = Ws2[(kb + 0) * L + c2], w1 = Ws2[(kb + 1) * L + c2];
            float2 w2 = Ws2[(kb + 2) * L + c2], w3 = Ws2[(kb + 3) * L + c2];
            acc.x += v.x * w0.x; acc.y += v.x * w0.y;
            acc.x += v.y * w1.x; acc.y += v.y * w1.y;
            acc.x += v.z * w2.x; acc.y += v.z * w2.y;
            acc.x += v.w * w3.x; acc.y += v.w * w3.y;
        }
        const float4* x4 = (const float4*)(Xls + rl * 36);
#pragma unroll
        for (int k4 = 0; k4 < 8; ++k4) {
            float4 v = x4[k4]; int kb = 64 + k4 * 4;
            float2 w0 = Ws2[(kb + 0) * L + c2], w1 = Ws2[(kb + 1) * L + c2];
            float2 w2 = Ws2[(kb + 2) * L + c2], w3 = Ws2[(kb + 3) * L + c2];
            acc.x += v.x * w0.x; acc.y += v.x * w0.y;
            acc.x += v.y * w1.x; acc.y += v.y * w1.y;
            acc.x += v.z * w2.x; acc.y += v.z * w2.y;
            acc.x += v.w * w3.x; acc.y += v.w * w3.y;
        }
        const float4* d4 = (const float4*)(Dws + rl * 68);
#pragma unroll
        for (int k4 = 0; k4 < 16; ++k4) {
            float4 v = d4[k4]; int kb = 96 + k4 * 4;
            float2 w0 = Ws2[(kb + 0) * L + c2], w1 = Ws2[(kb + 1) * L + c2];
            float2 w2 = Ws2[(kb + 2) * L + c2], w3 = Ws2[(kb + 3) * L + c2];
            acc.x += v.x * w0.x; acc.y += v.x * w0.y;
            acc.x += v.y * w1.x; acc.y += v.y * w1.y;
            acc.x += v.z * w2.x; acc.y += v.z * w2.y;
            acc.x += v.w * w3.x; acc.y += v.w * w3.y;
        }
        float2 o;
        o.x = 1.0f / (1.0f + __expf(-acc.x));
        o.y = 1.0f / (1.0f + __expf(-acc.y));
        ((float2*)out)[(size_t)(base + rl) * L + c2] = o;
    }
}

// ---------------- launch ----------------

extern "C" void kernel_launch(void* const* d_in, const int* in_sizes, int n_in,
                              void* d_out, int out_size, void* d_ws, size_t ws_size,
                              hipStream_t stream) {
    const float* x    = (const float*)d_in[0];
    const float* y    = (const float*)d_in[1];
    const int*   ei   = (const int*)  d_in[2];
    const float* dw   = (const float*)d_in[3];
    const int*   mask = (const int*)  d_in[4];
    const float* Wg0  = (const float*)d_in[5];
    const float* bg0  = (const float*)d_in[6];
    const float* Wg1  = (const float*)d_in[7];
    const float* bg1  = (const float*)d_in[8];
    const float* Wl   = (const float*)d_in[9];
    const float* bl   = (const float*)d_in[10];
    const float* Wf   = (const float*)d_in[11];
    const float* bf   = (const float*)d_in[12];
    float* out = (float*)d_out;

    const int N = in_sizes[0] / IN_DIM;
    const int E = in_sizes[2] / 2;
    const int* src = ei;
    const int* dst = ei + E;

    char* w = (char*)d_ws;
    size_t off = 0;
    auto alloc = [&](size_t bytes) -> char* {
        off = (off + 255) & ~(size_t)255;
        char* p = w + off; off += bytes; return p;
    };
    float* dinv   = (float*)alloc((size_t)N * 4);
    int*   deg    = (int*)  alloc((size_t)N * 4);
    int*   rowp   = (int*)  alloc((size_t)(N + 1) * 4);
    int*   cursor = (int*)  alloc((size_t)N * 4);
    int*   parts  = (int*)  alloc(512 * 4);
    int*   colx   = (int*)  alloc((size_t)E * 4);
    unsigned int* gbuf = (unsigned int*)alloc((size_t)N * (HID / 2) * 4);
    float* hbuf   = (float*)alloc((size_t)N * HID * 4);
    float* xlA    = (float*)alloc((size_t)N * OUT_F * 4);
    float* xlB    = (float*)alloc((size_t)N * OUT_F * 4);
    (void)ws_size; (void)n_in; (void)out_size;

    const int nbN = (N + 255) / 256;
    const int nbE = (E + 255) / 256;
    const int nbC = (N + 31) / 32;      // 32-row chunks -> 3125 blocks
    const int nbG = (N + 3) / 4;        // one node per wave, 4 waves/block

    (void)hipMemsetAsync(deg, 0, (size_t)N * 4, stream);
    count_deg_k<<<nbE, 256, 0, stream>>>(dst, deg, E);
    dinv_k<<<nbN, 256, 0, stream>>>(deg, dinv, N);
    scan_partials_k<<<nbN, 256, 0, stream>>>(deg, parts, N);
    scan_top_k<<<1, 512, 0, stream>>>(parts, nbN);
    scan_final_k<<<nbN, 256, 0, stream>>>(deg, parts, rowp, cursor, N, E);
    fill_csr_k<<<nbE, 256, 0, stream>>>(src, dst, cursor, colx, E);

    // feature path
    linear_scale_k<IN_DIM, HID, 32><<<nbC, 256, 0, stream>>>(x, Wg0, dinv, gbuf, N);
    gcn_gather_k<HID, false><<<nbG, 256, 0, stream>>>(gbuf, rowp, colx, dinv, bg0, nullptr, nullptr, hbuf, N);
    linear_scale_k<HID, HID, 32><<<nbC, 256, 0, stream>>>(hbuf, Wg1, dinv, gbuf, N);
    gcn_gather_k<HID, false><<<nbG, 256, 0, stream>>>(gbuf, rowp, colx, dinv, bg1, nullptr, nullptr, hbuf, N);

    // label path: 10 masked convs, ping-pong xlA/xlB
    const float* xl_cur = y;
    for (int j = 0; j < NUM_LBL; ++j) {
        float* xl_out = (j & 1) ? xlB : xlA;
        linear_scale_k<OUT_F, OUT_F, 32><<<nbC, 256, 0, stream>>>(xl_cur, Wl + (size_t)j * OUT_F * OUT_F, dinv, gbuf, N);
        gcn_gather_k<OUT_F, true><<<nbG, 256, 0, stream>>>(gbuf, rowp, colx, dinv, bl + (size_t)j * OUT_F, mask, y, xl_out, N);
        xl_cur = xl_out;
    }

    fuse_k<<<nbC, 256, 0, stream>>>(hbuf, xl_cur, dw, Wf, bf, out, N);
}

// Round 8
// 1285.385 us; speedup vs baseline: 2.6301x; 1.5093x over previous
//
#include <hip/hip_runtime.h>
#include <math.h>

static constexpr int IN_DIM  = 128;
static constexpr int HID     = 64;
static constexpr int OUT_F   = 32;
static constexpr int NUM_LBL = 10;

// bf16 pack/unpack via bit ops (ROCm bf16 API surface is unreliable across versions)
__device__ __forceinline__ unsigned int f2bf_lo(float f) {   // bf16 bits in low 16
    unsigned int u = __float_as_uint(f);
    return (u + 0x7fffu + ((u >> 16) & 1u)) >> 16;
}
__device__ __forceinline__ unsigned int pack_bf2(float a, float b) {
    return f2bf_lo(a) | (f2bf_lo(b) << 16);
}
__device__ __forceinline__ float bf2f_lo(unsigned int v) { return __uint_as_float(v << 16); }
__device__ __forceinline__ float bf2f_hi(unsigned int v) { return __uint_as_float(v & 0xffff0000u); }

// ---------------- graph setup kernels ----------------

__global__ void count_deg_k(const int* __restrict__ dst, int* __restrict__ deg, int E) {
    int e = blockIdx.x * 256 + threadIdx.x;
    if (e < E) atomicAdd(&deg[dst[e]], 1);
}

__global__ void dinv_k(const int* __restrict__ deg, float* __restrict__ dinv, int n) {
    int i = blockIdx.x * 256 + threadIdx.x;
    if (i < n) dinv[i] = rsqrtf((float)deg[i] + 1.0f);
}

__global__ void scan_partials_k(const int* __restrict__ deg, int* __restrict__ partials, int n) {
    __shared__ int s[256];
    int i = blockIdx.x * 256 + threadIdx.x;
    s[threadIdx.x] = (i < n) ? deg[i] : 0;
    __syncthreads();
    for (int st = 128; st > 0; st >>= 1) {
        if (threadIdx.x < st) s[threadIdx.x] += s[threadIdx.x + st];
        __syncthreads();
    }
    if (threadIdx.x == 0) partials[blockIdx.x] = s[0];
}

// single block, exclusive scan in place (nb <= 512)
__global__ void scan_top_k(int* __restrict__ partials, int nb) {
    __shared__ int s[512];
    int t = threadIdx.x;
    int v = (t < nb) ? partials[t] : 0;
    s[t] = v;
    __syncthreads();
    for (int off = 1; off < 512; off <<= 1) {
        int x = (t >= off) ? s[t - off] : 0;
        __syncthreads();
        s[t] += x;
        __syncthreads();
    }
    if (t < nb) partials[t] = s[t] - v;
}

__global__ void scan_final_k(const int* __restrict__ deg, const int* __restrict__ partials,
                             int* __restrict__ row_ptr, int* __restrict__ cursor, int n, int E) {
    __shared__ int s[256];
    int t = threadIdx.x;
    int i = blockIdx.x * 256 + t;
    int v = (i < n) ? deg[i] : 0;
    s[t] = v;
    __syncthreads();
    for (int off = 1; off < 256; off <<= 1) {
        int x = (t >= off) ? s[t - off] : 0;
        __syncthreads();
        s[t] += x;
        __syncthreads();
    }
    int excl = s[t] - v + partials[blockIdx.x];
    if (i < n) { row_ptr[i] = excl; cursor[i] = excl; }
    if (i == 0) row_ptr[n] = E;
}

__global__ void fill_csr_k(const int* __restrict__ src, const int* __restrict__ dst,
                           int* __restrict__ cursor, int* __restrict__ col, int E) {
    int e = blockIdx.x * 256 + threadIdx.x;
    if (e < E) {
        int pos = atomicAdd(&cursor[dst[e]], 1);
        col[pos] = src[e];
    }
}

// ---------------- compute kernels ----------------

// g[row, 2c2..2c2+1] = bf16x2( dinv[row] * x[row,:] @ W[:, 2c2..2c2+1] )
// Register-tiled: each thread owns acc[R] rows; k-loop OUTER loads W into regs
// once per k-step and applies to R rows. Reuse lives in registers by
// construction -> no LICM hoist, no spill (round-5 lesson: the outer row loop
// form spilled ~0.5 KB/thread to scratch = 460 MB of HBM writes).
// Row pad +4 floats: row stride mod 32 banks == 4 -> conflict-free b128 reads.
template<int K, int F, int R>
__global__ void __launch_bounds__(256, 2)
linear_scale_k(const float* __restrict__ x, const float* __restrict__ W,
               const float* __restrict__ dinv,
               unsigned int* __restrict__ g, int n) {
    constexpr int L = F / 2;            // packed col-pairs per row
    constexpr int TR = 256 / L;         // row-groups per block
    constexpr int CHUNK = TR * R;       // rows per block
    constexpr int KP = K + 4;           // padded row stride (floats)
    __shared__ float Ws[K * F];
    __shared__ float Xs[CHUNK * KP];
    __shared__ float Ds[CHUNK];
    {   // stage W (coalesced)
        const float4* W4 = (const float4*)W;
        float4* Ws4 = (float4*)Ws;
        for (int idx = threadIdx.x; idx < K * F / 4; idx += 256) Ws4[idx] = W4[idx];
    }
    int base = blockIdx.x * CHUNK;
    int nrows = min(CHUNK, n - base);
    {   // stage x chunk (coalesced global, padded LDS rows)
        const float4* X4 = (const float4*)(x + (size_t)base * K);
        for (int idx = threadIdx.x; idx < nrows * (K / 4); idx += 256) {
            int row = idx / (K / 4), kk = idx % (K / 4);
            *(float4*)(Xs + row * KP + kk * 4) = X4[idx];
        }
        if (threadIdx.x < nrows) Ds[threadIdx.x] = dinv[base + threadIdx.x];
    }
    __syncthreads();
    const float2* Ws2 = (const float2*)Ws;
    int c2 = threadIdx.x % L;
    int r0 = (threadIdx.x / L) * R;
    float2 acc[R];
#pragma unroll
    for (int r = 0; r < R; ++r) { acc[r].x = 0.f; acc[r].y = 0.f; }
#pragma unroll 4
    for (int k4 = 0; k4 < K / 4; ++k4) {
        float2 w0 = Ws2[(4 * k4 + 0) * L + c2];
        float2 w1 = Ws2[(4 * k4 + 1) * L + c2];
        float2 w2 = Ws2[(4 * k4 + 2) * L + c2];
        float2 w3 = Ws2[(4 * k4 + 3) * L + c2];
#pragma unroll
        for (int r = 0; r < R; ++r) {
            float4 xv = *(const float4*)(Xs + (r0 + r) * KP + k4 * 4);
            acc[r].x += xv.x * w0.x; acc[r].y += xv.x * w0.y;
            acc[r].x += xv.y * w1.x; acc[r].y += xv.y * w1.y;
            acc[r].x += xv.z * w2.x; acc[r].y += xv.z * w2.y;
            acc[r].x += xv.w * w3.x; acc[r].y += xv.w * w3.y;
        }
    }
#pragma unroll
    for (int r = 0; r < R; ++r) {
        int row = r0 + r;
        if (row < nrows) {
            float di = Ds[row];
            g[(size_t)(base + row) * L + c2] = pack_bf2(di * acc[r].x, di * acc[r].y);
        }
    }
}

// out[i,:] = dinv[i] * (sum_{src in nbr(i)} g[src,:] + g[i,:]) + bias; optional mask overwrite.
// One node per WAVE; lanes = L packed-slots x S edge-splits; shfl_xor reduce over splits.
template<int F, bool MASK>
__global__ void gcn_gather_k(const unsigned int* __restrict__ g, const int* __restrict__ row_ptr,
                             const int* __restrict__ col, const float* __restrict__ dinv,
                             const float* __restrict__ bias, const int* __restrict__ mask,
                             const float* __restrict__ y, float* __restrict__ out, int n) {
    constexpr int L = F / 2;            // packed lanes per node
    constexpr int S = 64 / L;           // edge-split ways (F=64 -> 2, F=32 -> 4)
    int lane = threadIdx.x & 63;
    int wid  = threadIdx.x >> 6;
    int c2 = lane % L;
    int sp = lane / L;
    int i = blockIdx.x * 4 + wid;
    if (i >= n) return;
    int beg = row_ptr[i], end = row_ptr[i + 1];
    float2 acc = {0.f, 0.f};
    for (int p = beg + sp; p < end; p += S) {
        int s = col[p];
        unsigned int v = g[(size_t)s * L + c2];
        acc.x += bf2f_lo(v);
        acc.y += bf2f_hi(v);
    }
#pragma unroll
    for (int m = 32; m >= L; m >>= 1) {
        acc.x += __shfl_xor(acc.x, m);
        acc.y += __shfl_xor(acc.y, m);
    }
    if (sp == 0) {
        unsigned int gi = g[(size_t)i * L + c2];
        float di = dinv[i];
        float2 v;
        v.x = di * (acc.x + bf2f_lo(gi)) + bias[2 * c2];
        v.y = di * (acc.y + bf2f_hi(gi)) + bias[2 * c2 + 1];
        if (MASK) {
            if (mask[i]) v = ((const float2*)y)[(size_t)i * L + c2];
        }
        ((float2*)out)[(size_t)i * L + c2] = v;
    }
}

// out[i,:] = sigmoid( [h|xl|dw] @ Wf + bf ); register-tiled like linear_scale_k.
// The three inputs are staged into ONE concatenated 160-wide LDS row (pad->164).
__global__ void __launch_bounds__(256, 2)
fuse_k(const float* __restrict__ h, const float* __restrict__ xl,
       const float* __restrict__ dw, const float* __restrict__ Wf,
       const float* __restrict__ bf, float* __restrict__ out, int n) {
    constexpr int L = 16;               // 16 f2-slots = 32 cols
    constexpr int TR = 16;
    constexpr int R = 2;
    constexpr int CHUNK = TR * R;       // 32
    constexpr int KP = 164;             // 160 + 4 pad
    __shared__ float Ws[160 * 32];
    __shared__ float Xs[CHUNK * KP];
    {
        const float4* W4 = (const float4*)Wf;
        float4* Ws4 = (float4*)Ws;
        for (int idx = threadIdx.x; idx < 160 * 32 / 4; idx += 256) Ws4[idx] = W4[idx];
    }
    int base = blockIdx.x * CHUNK;
    int nrows = min(CHUNK, n - base);
    {
        const float4* H4 = (const float4*)(h + (size_t)base * 64);
        for (int idx = threadIdx.x; idx < nrows * 16; idx += 256) {
            int row = idx / 16, kk = idx % 16;
            *(float4*)(Xs + row * KP + kk * 4) = H4[idx];
        }
        const float4* X4 = (const float4*)(xl + (size_t)base * 32);
        for (int idx = threadIdx.x; idx < nrows * 8; idx += 256) {
            int row = idx / 8, kk = idx % 8;
            *(float4*)(Xs + row * KP + 64 + kk * 4) = X4[idx];
        }
        const float4* D4 = (const float4*)(dw + (size_t)base * 64);
        for (int idx = threadIdx.x; idx < nrows * 16; idx += 256) {
            int row = idx / 16, kk = idx % 16;
            *(float4*)(Xs + row * KP + 96 + kk * 4) = D4[idx];
        }
    }
    __syncthreads();
    const float2* Ws2 = (const float2*)Ws;
    int c2 = threadIdx.x % L;
    int r0 = (threadIdx.x / L) * R;
    float2 acc[R];
#pragma unroll
    for (int r = 0; r < R; ++r) { acc[r].x = bf[2 * c2]; acc[r].y = bf[2 * c2 + 1]; }
#pragma unroll 4
    for (int k4 = 0; k4 < 40; ++k4) {
        float2 w0 = Ws2[(4 * k4 + 0) * L + c2];
        float2 w1 = Ws2[(4 * k4 + 1) * L + c2];
        float2 w2 = Ws2[(4 * k4 + 2) * L + c2];
        float2 w3 = Ws2[(4 * k4 + 3) * L + c2];
#pragma unroll
        for (int r = 0; r < R; ++r) {
            float4 xv = *(const float4*)(Xs + (r0 + r) * KP + k4 * 4);
            acc[r].x += xv.x * w0.x; acc[r].y += xv.x * w0.y;
            acc[r].x += xv.y * w1.x; acc[r].y += xv.y * w1.y;
            acc[r].x += xv.z * w2.x; acc[r].y += xv.z * w2.y;
            acc[r].x += xv.w * w3.x; acc[r].y += xv.w * w3.y;
        }
    }
#pragma unroll
    for (int r = 0; r < R; ++r) {
        int row = r0 + r;
        if (row < nrows) {
            float2 o;
            o.x = 1.0f / (1.0f + __expf(-acc[r].x));
            o.y = 1.0f / (1.0f + __expf(-acc[r].y));
            ((float2*)out)[(size_t)(base + row) * L + c2] = o;
        }
    }
}

// ---------------- launch ----------------

extern "C" void kernel_launch(void* const* d_in, const int* in_sizes, int n_in,
                              void* d_out, int out_size, void* d_ws, size_t ws_size,
                              hipStream_t stream) {
    const float* x    = (const float*)d_in[0];
    const float* y    = (const float*)d_in[1];
    const int*   ei   = (const int*)  d_in[2];
    const float* dw   = (const float*)d_in[3];
    const int*   mask = (const int*)  d_in[4];
    const float* Wg0  = (const float*)d_in[5];
    const float* bg0  = (const float*)d_in[6];
    const float* Wg1  = (const float*)d_in[7];
    const float* bg1  = (const float*)d_in[8];
    const float* Wl   = (const float*)d_in[9];
    const float* bl   = (const float*)d_in[10];
    const float* Wf   = (const float*)d_in[11];
    const float* bf   = (const float*)d_in[12];
    float* out = (float*)d_out;

    const int N = in_sizes[0] / IN_DIM;
    const int E = in_sizes[2] / 2;
    const int* src = ei;
    const int* dst = ei + E;

    char* w = (char*)d_ws;
    size_t off = 0;
    auto alloc = [&](size_t bytes) -> char* {
        off = (off + 255) & ~(size_t)255;
        char* p = w + off; off += bytes; return p;
    };
    float* dinv   = (float*)alloc((size_t)N * 4);
    int*   deg    = (int*)  alloc((size_t)N * 4);
    int*   rowp   = (int*)  alloc((size_t)(N + 1) * 4);
    int*   cursor = (int*)  alloc((size_t)N * 4);
    int*   parts  = (int*)  alloc(512 * 4);
    int*   colx   = (int*)  alloc((size_t)E * 4);
    unsigned int* gbuf = (unsigned int*)alloc((size_t)N * (HID / 2) * 4);
    float* hbuf   = (float*)alloc((size_t)N * HID * 4);
    float* xlA    = (float*)alloc((size_t)N * OUT_F * 4);
    float* xlB    = (float*)alloc((size_t)N * OUT_F * 4);
    (void)ws_size; (void)n_in; (void)out_size;

    const int nbN = (N + 255) / 256;
    const int nbE = (E + 255) / 256;
    const int nbC = (N + 31) / 32;      // CHUNK=32 rows per block (all shapes)
    const int nbG = (N + 3) / 4;        // one node per wave, 4 waves/block

    (void)hipMemsetAsync(deg, 0, (size_t)N * 4, stream);
    count_deg_k<<<nbE, 256, 0, stream>>>(dst, deg, E);
    dinv_k<<<nbN, 256, 0, stream>>>(deg, dinv, N);
    scan_partials_k<<<nbN, 256, 0, stream>>>(deg, parts, N);
    scan_top_k<<<1, 512, 0, stream>>>(parts, nbN);
    scan_final_k<<<nbN, 256, 0, stream>>>(deg, parts, rowp, cursor, N, E);
    fill_csr_k<<<nbE, 256, 0, stream>>>(src, dst, cursor, colx, E);

    // feature path
    linear_scale_k<IN_DIM, HID, 4><<<nbC, 256, 0, stream>>>(x, Wg0, dinv, gbuf, N);
    gcn_gather_k<HID, false><<<nbG, 256, 0, stream>>>(gbuf, rowp, colx, dinv, bg0, nullptr, nullptr, hbuf, N);
    linear_scale_k<HID, HID, 4><<<nbC, 256, 0, stream>>>(hbuf, Wg1, dinv, gbuf, N);
    gcn_gather_k<HID, false><<<nbG, 256, 0, stream>>>(gbuf, rowp, colx, dinv, bg1, nullptr, nullptr, hbuf, N);

    // label path: 10 masked convs, ping-pong xlA/xlB
    const float* xl_cur = y;
    for (int j = 0; j < NUM_LBL; ++j) {
        float* xl_out = (j & 1) ? xlB : xlA;
        linear_scale_k<OUT_F, OUT_F, 2><<<nbC, 256, 0, stream>>>(xl_cur, Wl + (size_t)j * OUT_F * OUT_F, dinv, gbuf, N);
        gcn_gather_k<OUT_F, true><<<nbG, 256, 0, stream>>>(gbuf, rowp, colx, dinv, bl + (size_t)j * OUT_F, mask, y, xl_out, N);
        xl_cur = xl_out;
    }

    fuse_k<<<nbC, 256, 0, stream>>>(hbuf, xl_cur, dw, Wf, bf, out, N);
}